// Round 9
// baseline (155.850 us; speedup 1.0000x reference)
//
#include <hip/hip_runtime.h>

#define SS 2048
#define DD 64
#define BH 32      // B*H
#define QSCALE 0.1803368801f   // 0.125 * log2(e)

typedef __attribute__((ext_vector_type(8))) short short8;
typedef __attribute__((ext_vector_type(4))) float floatx4;

__device__ __forceinline__ short f2bf(float x) {        // RNE
  union { float f; unsigned u; } un; un.f = x;
  unsigned r = (un.u + 0x7FFFu + ((un.u >> 16) & 1u)) >> 16;
  return (short)r;
}
__device__ __forceinline__ float fexp2(float x) {
  return __builtin_amdgcn_exp2f(x);
}
#define MFMA __builtin_amdgcn_mfma_f32_16x16x32_bf16

// slot c (0..31) -> physical k within 32-tile: quad=c>>3, h=(c>>2)&1, r=c&3
__device__ __forceinline__ int kperm(int c) {
  return (((c >> 2) & 1) << 4) + ((c >> 3) << 2) + (c & 3);
}

// ---------- merged pre-pass: K fp32->bf16 (same layout) + V fp32->bf16 tile-major ----------
// grid (bh, tile): linear%8 = bh%8 -> writes land in the SAME XCD L2 that
// sdpa_fused (grid x = bh) reads from.
__global__ __launch_bounds__(256) void prep_kv(const float* __restrict__ K,
                                               const float* __restrict__ V,
                                               short* __restrict__ Kbf,
                                               short* __restrict__ Vtp) {
  __shared__ short Ts[64][72];
  const int bh = blockIdx.x;
  const int r0 = blockIdx.y * 64;
  const int t  = threadIdx.x;
  // V: 64x64 fp32 tile -> bf16 in LDS
  {
    const int r = t >> 2, c = (t & 3) * 16;
    const float* g = V + ((size_t)bh * SS + r0 + r) * DD + c;
    floatx4 a = *(const floatx4*)g;
    floatx4 b = *(const floatx4*)(g + 4);
    floatx4 cc = *(const floatx4*)(g + 8);
    floatx4 dd = *(const floatx4*)(g + 12);
    short8 x0, x1;
    x0[0]=f2bf(a[0]); x0[1]=f2bf(a[1]); x0[2]=f2bf(a[2]); x0[3]=f2bf(a[3]);
    x0[4]=f2bf(b[0]); x0[5]=f2bf(b[1]); x0[6]=f2bf(b[2]); x0[7]=f2bf(b[3]);
    x1[0]=f2bf(cc[0]);x1[1]=f2bf(cc[1]);x1[2]=f2bf(cc[2]);x1[3]=f2bf(cc[3]);
    x1[4]=f2bf(dd[0]);x1[5]=f2bf(dd[1]);x1[6]=f2bf(dd[2]);x1[7]=f2bf(dd[3]);
    *(short8*)&Ts[r][c] = x0;
    *(short8*)&Ts[r][c + 8] = x1;
  }
  // K: straight convert (independent of LDS; overlaps transpose)
  {
    const size_t i = ((size_t)bh * SS + r0) * DD + (size_t)t * 16;
    floatx4 a = *(const floatx4*)(K + i);
    floatx4 b = *(const floatx4*)(K + i + 4);
    floatx4 cc = *(const floatx4*)(K + i + 8);
    floatx4 dd = *(const floatx4*)(K + i + 12);
    short8 x0, x1;
    x0[0]=f2bf(a[0]); x0[1]=f2bf(a[1]); x0[2]=f2bf(a[2]); x0[3]=f2bf(a[3]);
    x0[4]=f2bf(b[0]); x0[5]=f2bf(b[1]); x0[6]=f2bf(b[2]); x0[7]=f2bf(b[3]);
    x1[0]=f2bf(cc[0]);x1[1]=f2bf(cc[1]);x1[2]=f2bf(cc[2]);x1[3]=f2bf(cc[3]);
    x1[4]=f2bf(dd[0]);x1[5]=f2bf(dd[1]);x1[6]=f2bf(dd[2]);x1[7]=f2bf(dd[3]);
    *(short8*)(Kbf + i) = x0;
    *(short8*)(Kbf + i + 8) = x1;
  }
  __syncthreads();
  // V write-out: [bh][tile][d][32], k-permuted
  {
    const int d = t >> 2, cblk = (t & 3) * 16;
    short8 y0, y1;
    #pragma unroll
    for (int jj = 0; jj < 8; ++jj) {
      const int c0 = cblk + jj, c1 = cblk + 8 + jj;
      y0[jj] = Ts[(c0 & 32) + kperm(c0 & 31)][d];
      y1[jj] = Ts[(c1 & 32) + kperm(c1 & 31)][d];
    }
    const int kt  = (r0 + cblk) >> 5;
    const int kin = cblk & 31;           // 0 or 16
    short* o = Vtp + (((size_t)bh * 64 + kt) * 64 + d) * 32 + kin;
    *(short8*)o = y0;
    *(short8*)(o + 8) = y1;
  }
}

// pack 4 exp'd floats into bf16 pairs via v_cvt_pk_bf16_f32 (RNE; no builtin).
#define CVTPK(DST_, A_, B_) \
  __asm__("v_cvt_pk_bf16_f32 %0, %1, %2" : "=v"(DST_) : "v"(A_), "v"(B_))

// per-tile compute, fragments loaded DIRECTLY from global (L2-resident).
// KT_: k-tile index. DIAG_=1: this wave's diagonal tile
// (strip A local q = l16, strip B local q = l16+16; tB0 vacuously unmasked).
#define TILE32(KT_, DIAG_)                                                   \
  {                                                                          \
    const short* kg = kbase + (size_t)(KT_) * 2048;                          \
    const short* vg = vtb   + (size_t)(KT_) * 2048;                          \
    short8 kb00 = *(const short8*)(kg + kofs);                               \
    short8 kb01 = *(const short8*)(kg + kofs + 32);                          \
    short8 kb10 = *(const short8*)(kg + kofs + 1024);                        \
    short8 kb11 = *(const short8*)(kg + kofs + 1056);                        \
    short8 vt0 = *(const short8*)(vg + vofs);                                \
    short8 vt1 = *(const short8*)(vg + vofs + 512);                          \
    short8 vt2 = *(const short8*)(vg + vofs + 1024);                         \
    short8 vt3 = *(const short8*)(vg + vofs + 1536);                         \
    __builtin_amdgcn_s_setprio(1);                                           \
    floatx4 tA0 = z, tA1 = z, tB0 = z, tB1 = z;                              \
    tA0 = MFMA(kb00, qaA0, tA0, 0, 0, 0); tA0 = MFMA(kb01, qaA1, tA0, 0, 0, 0);\
    tA1 = MFMA(kb10, qaA0, tA1, 0, 0, 0); tA1 = MFMA(kb11, qaA1, tA1, 0, 0, 0);\
    tB0 = MFMA(kb00, qaB0, tB0, 0, 0, 0); tB0 = MFMA(kb01, qaB1, tB0, 0, 0, 0);\
    tB1 = MFMA(kb10, qaB0, tB1, 0, 0, 0); tB1 = MFMA(kb11, qaB1, tB1, 0, 0, 0);\
    if (DIAG_) {                                                             \
      _Pragma("unroll")                                                      \
      for (int r = 0; r < 4; ++r) {                                          \
        tA0[r] = (quad * 4 + r      <= l16) ? tA0[r] : -1e30f;               \
        tA1[r] = (quad * 4 + r + 16 <= l16) ? tA1[r] : -1e30f;               \
        tB1[r] = (quad * 4 + r      <= l16) ? tB1[r] : -1e30f;               \
      }                                                                      \
    }                                                                        \
    _Pragma("unroll")                                                        \
    for (int r = 0; r < 4; ++r) {                                            \
      tA0[r] = fexp2(tA0[r]); tA1[r] = fexp2(tA1[r]);                        \
      tB0[r] = fexp2(tB0[r]); tB1[r] = fexp2(tB1[r]);                        \
    }                                                                        \
    union { unsigned u[4]; short8 s; } upA, upB;                             \
    CVTPK(upA.u[0], tA0[0], tA0[1]); CVTPK(upA.u[1], tA0[2], tA0[3]);        \
    CVTPK(upA.u[2], tA1[0], tA1[1]); CVTPK(upA.u[3], tA1[2], tA1[3]);        \
    CVTPK(upB.u[0], tB0[0], tB0[1]); CVTPK(upB.u[1], tB0[2], tB0[3]);        \
    CVTPK(upB.u[2], tB1[0], tB1[1]); CVTPK(upB.u[3], tB1[2], tB1[3]);        \
    short8 paA = upA.s, paB = upB.s;                                         \
    sA = MFMA(ones, paA, sA, 0, 0, 0);                                       \
    sB = MFMA(ones, paB, sB, 0, 0, 0);                                       \
    oA0 = MFMA(vt0, paA, oA0, 0, 0, 0); oA1 = MFMA(vt1, paA, oA1, 0, 0, 0);  \
    oA2 = MFMA(vt2, paA, oA2, 0, 0, 0); oA3 = MFMA(vt3, paA, oA3, 0, 0, 0);  \
    oB0 = MFMA(vt0, paB, oB0, 0, 0, 0); oB1 = MFMA(vt1, paB, oB1, 0, 0, 0);  \
    oB2 = MFMA(vt2, paB, oB2, 0, 0, 0); oB3 = MFMA(vt3, paB, oB3, 0, 0, 0);  \
    __builtin_amdgcn_s_setprio(0);                                           \
  }

// ---------- single-pass fused SDPA, BARRIER-FREE main loop ----------
// grid (bh=32, y=32) = 1024 blocks = 4/CU = 16 waves/CU (4/SIMD).
// wave w = (qp=w>>1, kp=w&1): qp picks 32 q-rows; kp picks tile parity.
// NEW vs R8: NO LDS staging. K/V working set is 2 MB/XCD (L2-fits; R5 FETCH
// confirms) and the prepped layouts make fragment loads coalesced global
// reads -> load straight to VGPRs. Deletes the per-group vmcnt(0)+barrier
// lockstep (66 rendezvous/CU) that R5-R8 showed was the dominant stall;
// waves run fully self-paced, compiler pipelines loads across iterations.
__global__ __launch_bounds__(256, 4) void sdpa_fused(
    const float* __restrict__ Q, const short* __restrict__ Kbf,
    const short* __restrict__ Vtp, float* __restrict__ Og) {
  __shared__ __align__(16) float lf[4352];   // 17 KB, final combine only

  const int tid  = threadIdx.x;
  const int w    = tid >> 6;              // 0..3
  const int lane = tid & 63;
  const int quad = lane >> 4;
  const int l16  = lane & 15;
  const int qp   = w >> 1;                // q-half owner
  const int kp   = w & 1;                 // k-tile parity owner

  const int bh = blockIdx.x;              // linear%8 = bh%8 -> XCD-local K/V in L2
  const int y  = blockIdx.y;              // 0..31
  const int qt = (y < 16) ? (31 - y) : (y - 16);   // 64-row q-tile index

  const size_t base = (size_t)bh * SS * DD;
  const short* kbase = Kbf + base;                 // [k][d], tiles contiguous
  const short* vtb   = Vtp + base;                 // [tile][d][32]

  // direct-global fragment offsets (shorts):
  // K row l16 (+16), d-halves quad*8 / +32; V slot-major 16B per lane.
  const int kofs = l16 * 64 + quad * 8;
  const int vofs = l16 * 32 + quad * 8;

  short8 ones;
  #pragma unroll
  for (int r = 0; r < 8; ++r) ones[r] = (short)0x3F80;   // bf16 1.0
  const floatx4 z = {0.f, 0.f, 0.f, 0.f};

  const int qA = qt * 64 + qp * 32;       // strip A rows; strip B = +16
  const int qB = qA + 16;

  // ---- Q fragments for both strips (B-operand layout) ----
  short8 qaA0, qaA1, qaB0, qaB1;
  {
    const float* ga = Q + base + (size_t)(qA + l16) * DD + quad * 8;
    const float* gb = Q + base + (size_t)(qB + l16) * DD + quad * 8;
    floatx4 a0 = *(const floatx4*)ga,        a1 = *(const floatx4*)(ga + 4);
    floatx4 a2 = *(const floatx4*)(ga + 32), a3 = *(const floatx4*)(ga + 36);
    floatx4 b0 = *(const floatx4*)gb,        b1 = *(const floatx4*)(gb + 4);
    floatx4 b2 = *(const floatx4*)(gb + 32), b3 = *(const floatx4*)(gb + 36);
    #pragma unroll
    for (int r = 0; r < 4; ++r) {
      qaA0[r] = f2bf(a0[r] * QSCALE); qaA0[4 + r] = f2bf(a1[r] * QSCALE);
      qaA1[r] = f2bf(a2[r] * QSCALE); qaA1[4 + r] = f2bf(a3[r] * QSCALE);
      qaB0[r] = f2bf(b0[r] * QSCALE); qaB0[4 + r] = f2bf(b1[r] * QSCALE);
      qaB1[r] = f2bf(b2[r] * QSCALE); qaB1[4 + r] = f2bf(b3[r] * QSCALE);
    }
  }

  floatx4 oA0 = z, oA1 = z, oA2 = z, oA3 = z;   // O^T: q = l16, d = i*16+quad*4+r
  floatx4 oB0 = z, oB1 = z, oB2 = z, oB3 = z;
  floatx4 sA = z, sB = z;                       // row-sum accumulators (replicated)

  // wave's tiles: kt = 2*i + kp, i = 0..nt-1.
  //   (kp=0,qp=0): nt=qt+1, last is diag (ktd=2qt).
  //   (kp=0,qp=1): nt=qt+1, all full (tile 2qt max k 64qt+31 < q min 64qt+32).
  //   (kp=1,qp=0): nt=qt,   all full; tile 2qt+1 is above-diag -> skipped.
  //   (kp=1,qp=1): nt=qt+1, last is diag (ktd=2qt+1).
  const int nt = (kp == 1 && qp == 0) ? qt : (qt + 1);
  const int ndiag = (kp == qp) ? (nt - 1) : nt;   // iterations before diag

  #pragma unroll 2
  for (int i = 0; i < ndiag; ++i) {
    TILE32(2 * i + kp, 0)
  }
  if (kp == qp) {               // own diagonal tile (always exists: ndiag=nt-1>=0)
    TILE32(2 * (nt - 1) + kp, 1)
  }

  // ---- cross-wave combine: kp=1 partials -> kp=0 via LDS ----
  __syncthreads();
  if (kp) {
    floatx4* dst = (floatx4*)&lf[qp * 2048];
    dst[0 * 64 + lane] = oA0; dst[1 * 64 + lane] = oA1;
    dst[2 * 64 + lane] = oA2; dst[3 * 64 + lane] = oA3;
    dst[4 * 64 + lane] = oB0; dst[5 * 64 + lane] = oB1;
    dst[6 * 64 + lane] = oB2; dst[7 * 64 + lane] = oB3;
    lf[4096 + qp * 128 + lane]      = sA[0];
    lf[4096 + qp * 128 + 64 + lane] = sB[0];
  }
  __syncthreads();
  if (!kp) {
    const floatx4* src = (const floatx4*)&lf[qp * 2048];
    oA0 += src[0 * 64 + lane]; oA1 += src[1 * 64 + lane];
    oA2 += src[2 * 64 + lane]; oA3 += src[3 * 64 + lane];
    oB0 += src[4 * 64 + lane]; oB1 += src[5 * 64 + lane];
    oB2 += src[6 * 64 + lane]; oB3 += src[7 * 64 + lane];
    const float invA = 1.0f / (sA[0] + lf[4096 + qp * 128 + lane]);
    const float invB = 1.0f / (sB[0] + lf[4096 + qp * 128 + 64 + lane]);
    oA0 *= invA; oA1 *= invA; oA2 *= invA; oA3 *= invA;
    oB0 *= invB; oB1 *= invB; oB2 *= invB; oB3 *= invB;
    float* ra = Og + base + (size_t)(qA + l16) * DD + quad * 4;
    float* rb = Og + base + (size_t)(qB + l16) * DD + quad * 4;
    *(floatx4*)(ra)      = oA0;
    *(floatx4*)(ra + 16) = oA1;
    *(floatx4*)(ra + 32) = oA2;
    *(floatx4*)(ra + 48) = oA3;
    *(floatx4*)(rb)      = oB0;
    *(floatx4*)(rb + 16) = oB1;
    *(floatx4*)(rb + 32) = oB2;
    *(floatx4*)(rb + 48) = oB3;
  }
}

extern "C" void kernel_launch(void* const* d_in, const int* in_sizes, int n_in,
                              void* d_out, int out_size, void* d_ws, size_t ws_size,
                              hipStream_t stream) {
  (void)in_sizes; (void)n_in; (void)out_size; (void)ws_size;
  const float* q = (const float*)d_in[0];
  const float* k = (const float*)d_in[1];
  const float* v = (const float*)d_in[2];
  float* o = (float*)d_out;

  short* Kbf = (short*)d_ws;                               // 8 MB
  short* Vtp = Kbf + (size_t)BH * SS * DD;                 // 8 MB

  prep_kv<<<dim3(BH, SS / 64), 256, 0, stream>>>(k, v, Kbf, Vtp);
  sdpa_fused<<<dim3(BH, 32), 256, 0, stream>>>(q, Kbf, Vtp, o);
}